// Round 4
// baseline (247.946 us; speedup 1.0000x reference)
//
#include <hip/hip_runtime.h>
#include <hip/hip_cooperative_groups.h>
#include <math.h>

namespace cg = cooperative_groups;

#define V_ 32000
#define E_ 1024
#define H_ 1024
#define S_ 2048

typedef __attribute__((ext_vector_type(8))) short bf16x8;
typedef __attribute__((ext_vector_type(8))) unsigned short u16x8;
typedef __attribute__((ext_vector_type(4))) float f32x4;

typedef __attribute__((address_space(1))) const unsigned int gu32;
typedef __attribute__((address_space(3))) unsigned int lu32;

__device__ __forceinline__ float sigmoidf_(float x) { return 1.0f / (1.0f + expf(-x)); }

__device__ __forceinline__ unsigned short f2bf(float f) {
    unsigned int u = __builtin_bit_cast(unsigned int, f);
    unsigned int r = (u + 0x7fffu + ((u >> 16) & 1u)) >> 16;
    return (unsigned short)r;
}
__device__ __forceinline__ float bf2f(unsigned short u) {
    return __builtin_bit_cast(float, ((unsigned int)u) << 16);
}
__device__ __forceinline__ u16x8 pack8(float4 a, float4 b) {
    u16x8 p;
    p[0] = f2bf(a.x); p[1] = f2bf(a.y); p[2] = f2bf(a.z); p[3] = f2bf(a.w);
    p[4] = f2bf(b.x); p[5] = f2bf(b.y); p[6] = f2bf(b.z); p[7] = f2bf(b.w);
    return p;
}
__device__ __forceinline__ void gload16(const void* g, void* l) {
    __builtin_amdgcn_global_load_lds((gu32*)g, (lu32*)l, 16, 0, 0);
}

struct Params {
    const float *enc, *last_context, *h0, *c0, *emb;
    const float *W_ih, *W_hh, *b_ih, *b_hh;
    const float *W_attn, *b_attn, *v, *W_ah, *b_ah, *W_out, *b_out;
    const int* word;
    float *out_logits, *out_ht, *out_c, *out_htt, *out_w;
    float *ws_ht, *ws_q, *ws_expw, *ws_ctx, *ws_htt, *gS, *gSL, *spart;
    unsigned short *encb, *wab;
};

// 256 blocks x 512 threads, cooperative. 1 block/CU (48 KB LDS).
__global__ __launch_bounds__(512) void mega(Params p)
{
    cg::grid_group grid = cg::this_grid();
    __shared__ __attribute__((aligned(16))) unsigned char smem[49152];
    const int b = blockIdx.x, tid = threadIdx.x;
    const int wave = tid >> 6, lane = tid & 63;

    // =========== P0: k1 LSTM (waves 0-3) || bf16 conversion (waves 4-7) ===========
    if (wave < 4) {
        int j = b * 4 + wave;           // 0..1023
        const float* embrow = p.emb + (size_t)p.word[0] * E_;
        float g4[4];
        #pragma unroll
        for (int r = 0; r < 4; ++r) {
            int row = j + r * H_;
            const float* wi = p.W_ih + (size_t)row * (E_ + H_);
            const float* wh = p.W_hh + (size_t)row * H_;
            float acc = 0.f;
            #pragma unroll
            for (int it = 0; it < 8; ++it) {
                int idx = (lane + it * 64) * 4;
                float4 wv = *(const float4*)(wi + idx);
                float4 xv = (idx < H_) ? *(const float4*)(p.last_context + idx)
                                       : *(const float4*)(embrow + (idx - H_));
                acc = fmaf(wv.x, xv.x, acc); acc = fmaf(wv.y, xv.y, acc);
                acc = fmaf(wv.z, xv.z, acc); acc = fmaf(wv.w, xv.w, acc);
            }
            #pragma unroll
            for (int it = 0; it < 4; ++it) {
                int idx = (lane + it * 64) * 4;
                float4 wv = *(const float4*)(wh + idx);
                float4 hv = *(const float4*)(p.h0 + idx);
                acc = fmaf(wv.x, hv.x, acc); acc = fmaf(wv.y, hv.y, acc);
                acc = fmaf(wv.z, hv.z, acc); acc = fmaf(wv.w, hv.w, acc);
            }
            #pragma unroll
            for (int m = 32; m; m >>= 1) acc += __shfl_down(acc, m, 64);
            g4[r] = acc;   // valid on lane 0
        }
        if (lane == 0) {
            float gi = g4[0] + p.b_ih[j]          + p.b_hh[j];
            float gf = g4[1] + p.b_ih[j + H_]     + p.b_hh[j + H_];
            float gg = g4[2] + p.b_ih[j + 2*H_]   + p.b_hh[j + 2*H_];
            float go = g4[3] + p.b_ih[j + 3*H_]   + p.b_hh[j + 3*H_];
            float c  = sigmoidf_(gf) * p.c0[j] + sigmoidf_(gi) * tanhf(gg);
            float ht = sigmoidf_(go) * tanhf(c);
            p.out_c[j]  = c;
            p.out_ht[j] = ht;
            p.ws_ht[j]  = ht;
        }
    } else {
        // bf16 conversion: 393216 granules over 65536 lanes -> 6 each
        int cid = (b * 4 + (wave - 4)) * 64 + lane;
        const int ENC_CH = (S_ * E_) / 8;
        #pragma unroll
        for (int i = 0; i < 6; ++i) {
            int idx = cid + i * 65536;
            const float* src;
            unsigned short* dst;
            if (idx < ENC_CH) {
                src = p.enc + (size_t)idx * 8;
                dst = p.encb + (size_t)idx * 8;
            } else {
                int w = idx - ENC_CH;
                int h = w >> 7, off = (w & 127) * 8;
                src = p.W_attn + (size_t)h * (E_ + H_) + H_ + off;
                dst = p.wab + (size_t)h * E_ + off;
            }
            float4 a = *(const float4*)src;
            float4 bq = *(const float4*)(src + 4);
            *(u16x8*)dst = pack8(a, bq);
        }
    }
    if (b == 0) {   // zero accumulators for this call
        p.ws_ctx[tid] = 0.f;
        p.ws_ctx[tid + 512] = 0.f;
        if (tid == 0) { *p.gS = 0.f; *p.gSL = 0.f; }
    }
    grid.sync();

    // =========== P1: k2  q = Wa_h @ ht + b_attn ===========
    if (wave < 4) {
        int h = b * 4 + wave;
        const float* row = p.W_attn + (size_t)h * (E_ + H_);
        float acc = 0.f;
        #pragma unroll
        for (int it = 0; it < 4; ++it) {
            int idx = (lane + it * 64) * 4;
            float4 wv = *(const float4*)(row + idx);
            float4 hv = *(const float4*)(p.ws_ht + idx);
            acc = fmaf(wv.x, hv.x, acc); acc = fmaf(wv.y, hv.y, acc);
            acc = fmaf(wv.z, hv.z, acc); acc = fmaf(wv.w, hv.w, acc);
        }
        #pragma unroll
        for (int m = 32; m; m >>= 1) acc += __shfl_down(acc, m, 64);
        if (lane == 0) p.ws_q[h] = acc + p.b_attn[h];
    }
    grid.sync();

    // =========== P2: k3b GEMM -> spart ===========
    {
        unsigned short* As = (unsigned short*)smem;            // 2 x 8192 shorts
        unsigned short* Bs = (unsigned short*)(smem + 32768);  // 2 x 4096 shorts
        int bx = b & 15, by = b >> 4;
        int s0 = bx * 128, h0 = by * 64;
        int srow = tid >> 3;
        int lch  = ((tid & 7) ^ (srow & 7)) * 8;
        const unsigned short* aSrc0 = p.encb + (size_t)(s0 + srow) * E_ + lch;
        const unsigned short* aSrc1 = p.encb + (size_t)(s0 + 64 + srow) * E_ + lch;
        const unsigned short* bSrc  = p.wab  + (size_t)(h0 + srow) * E_ + lch;

        int wr = (wave >> 1) * 32, wc = (wave & 1) * 32;
        int fc = lane & 15, g = lane >> 4;
        int aRow[2], bRow[2], pc[2];
        #pragma unroll
        for (int m = 0; m < 2; ++m) aRow[m] = (wr + m * 16 + fc) * 64;
        #pragma unroll
        for (int n = 0; n < 2; ++n) bRow[n] = (wc + n * 16 + fc) * 64;
        #pragma unroll
        for (int kk = 0; kk < 2; ++kk) pc[kk] = ((kk * 4 + g) ^ (fc & 7)) * 8;

        f32x4 acc[2][2];
        #pragma unroll
        for (int m = 0; m < 2; ++m)
            #pragma unroll
            for (int n = 0; n < 2; ++n)
                acc[m][n] = (f32x4){0.f, 0.f, 0.f, 0.f};

        gload16(aSrc0, As + tid * 8);
        gload16(aSrc1, As + (tid + 512) * 8);
        gload16(bSrc,  Bs + tid * 8);
        __syncthreads();

        int cur = 0;
        for (int t = 0; t < 16; ++t) {
            if (t < 15) {
                int k0 = (t + 1) * 64;
                gload16(aSrc0 + k0, As + (cur ^ 1) * 8192 + tid * 8);
                gload16(aSrc1 + k0, As + (cur ^ 1) * 8192 + (tid + 512) * 8);
                gload16(bSrc  + k0, Bs + (cur ^ 1) * 4096 + tid * 8);
            }
            #pragma unroll
            for (int kk = 0; kk < 2; ++kk) {
                bf16x8 af[2], bf2[2];
                #pragma unroll
                for (int m = 0; m < 2; ++m)
                    af[m] = *(const bf16x8*)(As + cur * 8192 + aRow[m] + pc[kk]);
                #pragma unroll
                for (int n = 0; n < 2; ++n)
                    bf2[n] = *(const bf16x8*)(Bs + cur * 4096 + bRow[n] + pc[kk]);
                #pragma unroll
                for (int m = 0; m < 2; ++m)
                    #pragma unroll
                    for (int n = 0; n < 2; ++n)
                        acc[m][n] = __builtin_amdgcn_mfma_f32_16x16x32_bf16(
                            af[m], bf2[n], acc[m][n], 0, 0, 0);
            }
            __syncthreads();
            cur ^= 1;
        }

        float qv[2], vv[2];
        #pragma unroll
        for (int n = 0; n < 2; ++n) {
            int col = h0 + wc + n * 16 + fc;
            qv[n] = p.ws_q[col];
            vv[n] = p.v[col];
        }
        int part = by * 2 + (wave & 1);
        #pragma unroll
        for (int m = 0; m < 2; ++m) {
            #pragma unroll
            for (int j = 0; j < 4; ++j) {
                float pp = 0.f;
                #pragma unroll
                for (int n = 0; n < 2; ++n)
                    pp += tanhf(acc[m][n][j] + qv[n]) * vv[n];
                #pragma unroll
                for (int mask = 8; mask; mask >>= 1) pp += __shfl_xor(pp, mask, 64);
                if (fc == 0)
                    p.spart[(size_t)(s0 + wr + m * 16 + g * 4 + j) * 32 + part] = pp;
            }
        }
    }
    grid.sync();

    // =========== P3: scores -> exp, partial sums (max-free softmax) ===========
    {
        float* sred = (float*)smem;
        int s = b * 8 + wave;
        float val = 0.f;
        if (lane < 32) val = p.spart[(size_t)s * 32 + lane];
        #pragma unroll
        for (int mask = 16; mask; mask >>= 1) val += __shfl_xor(val, mask, 64);
        if (lane == 0) {
            float e = expf(val);
            p.ws_expw[s] = e;
            sred[wave] = e;
        }
        __syncthreads();
        if (tid == 0) {
            float bs = 0.f;
            #pragma unroll
            for (int i = 0; i < 8; ++i) bs += sred[i];
            atomicAdd(p.gS, bs);
        }
    }
    grid.sync();

    // =========== P5: w output + context = w @ enc (bf16) ===========
    {
        float invS = 1.0f / (*p.gS);
        if (b == 0) {
            #pragma unroll
            for (int i = 0; i < 4; ++i) {
                int s = tid + i * 512;
                p.out_w[s] = p.ws_expw[s] * invS;
            }
        }
        int ex = b & 3, sg = b >> 2;
        int e = ex * 256 + (tid & 255), shalf = tid >> 8;
        int sbase = sg * 32 + shalf * 16;
        float acc = 0.f;
        #pragma unroll
        for (int ss = 0; ss < 16; ++ss) {
            int s = sbase + ss;
            acc = fmaf(p.ws_expw[s] * invS, bf2f(p.encb[(size_t)s * E_ + e]), acc);
        }
        atomicAdd(&p.ws_ctx[e], acc);
    }
    grid.sync();

    // =========== P6: ht_tilda = tanh(W_ah @ [ctx, ht] + b_ah) ===========
    if (wave < 4) {
        int h = b * 4 + wave;
        const float* row = p.W_ah + (size_t)h * (E_ + H_);
        float acc = 0.f;
        #pragma unroll
        for (int it = 0; it < 8; ++it) {
            int idx = (lane + it * 64) * 4;
            float4 wv = *(const float4*)(row + idx);
            float4 xv = (idx < E_) ? *(const float4*)(p.ws_ctx + idx)
                                   : *(const float4*)(p.ws_ht + (idx - E_));
            acc = fmaf(wv.x, xv.x, acc); acc = fmaf(wv.y, xv.y, acc);
            acc = fmaf(wv.z, xv.z, acc); acc = fmaf(wv.w, xv.w, acc);
        }
        #pragma unroll
        for (int m = 32; m; m >>= 1) acc += __shfl_down(acc, m, 64);
        if (lane == 0) {
            float val = tanhf(acc + p.b_ah[h]);
            p.out_htt[h] = val;
            p.ws_htt[h]  = val;
        }
    }
    grid.sync();

    // =========== P7: logits + exp partial sums (max-free lse) ===========
    {
        float* wes = (float*)smem;
        int rbase = b * 125;
        float esum = 0.f;
        for (int r = 0; r < 16; ++r) {
            int rl = wave * 16 + r;
            if (rl < 125) {
                int row = rbase + rl;
                const float* wrp = p.W_out + (size_t)row * H_;
                float acc = 0.f;
                #pragma unroll
                for (int it = 0; it < 4; ++it) {
                    int idx = (lane + it * 64) * 4;
                    float4 wv = *(const float4*)(wrp + idx);
                    float4 hv = *(const float4*)(p.ws_htt + idx);
                    acc = fmaf(wv.x, hv.x, acc); acc = fmaf(wv.y, hv.y, acc);
                    acc = fmaf(wv.z, hv.z, acc); acc = fmaf(wv.w, hv.w, acc);
                }
                #pragma unroll
                for (int m = 32; m; m >>= 1) acc += __shfl_down(acc, m, 64);
                if (lane == 0) {
                    float lg = acc + p.b_out[row];
                    p.out_logits[row] = lg;
                    esum += expf(lg);
                }
            }
        }
        if (lane == 0) wes[wave] = esum;
        __syncthreads();
        if (tid == 0) {
            float bs = 0.f;
            #pragma unroll
            for (int i = 0; i < 8; ++i) bs += wes[i];
            atomicAdd(p.gSL, bs);
        }
    }
    grid.sync();

    // =========== P8: out_logits -= lse ===========
    {
        float lse = logf(*p.gSL);
        if (tid < 125) p.out_logits[b * 125 + tid] -= lse;
    }
}

extern "C" void kernel_launch(void* const* d_in, const int* in_sizes, int n_in,
                              void* d_out, int out_size, void* d_ws, size_t ws_size,
                              hipStream_t stream) {
    Params prm;
    prm.enc          = (const float*)d_in[0];
    prm.word         = (const int*)  d_in[1];
    prm.last_context = (const float*)d_in[2];
    prm.h0           = (const float*)d_in[3];
    prm.c0           = (const float*)d_in[4];
    prm.emb          = (const float*)d_in[5];
    prm.W_ih         = (const float*)d_in[6];
    prm.W_hh         = (const float*)d_in[7];
    prm.b_ih         = (const float*)d_in[8];
    prm.b_hh         = (const float*)d_in[9];
    prm.W_attn       = (const float*)d_in[10];
    prm.b_attn       = (const float*)d_in[11];
    prm.v            = (const float*)d_in[12];
    prm.W_ah         = (const float*)d_in[13];
    prm.b_ah         = (const float*)d_in[14];
    prm.W_out        = (const float*)d_in[15];
    prm.b_out        = (const float*)d_in[16];

    float* out = (float*)d_out;
    prm.out_logits = out;                 // 32000
    prm.out_ht     = out + V_;            // 1024
    prm.out_c      = out + V_ + H_;       // 1024
    prm.out_htt    = out + V_ + 2 * H_;   // 1024
    prm.out_w      = out + V_ + 3 * H_;   // 2048

    float* ws = (float*)d_ws;
    prm.ws_ht   = ws;            // 1024
    prm.ws_q    = ws + 1024;     // 1024
    prm.ws_expw = ws + 2048;     // 2048
    prm.ws_ctx  = ws + 4096;     // 1024
    prm.ws_htt  = ws + 5120;     // 1024
    prm.gS      = ws + 6144;     // 1
    prm.gSL     = ws + 6145;     // 1
    prm.spart   = ws + 8192;     // 2048*32
    prm.encb    = (unsigned short*)(ws + 73728);        // 2048*1024 bf16
    prm.wab     = prm.encb + (size_t)S_ * E_;           // 1024*1024 bf16

    void* args[] = { &prm };
    hipLaunchCooperativeKernel((void*)mega, dim3(256), dim3(512), args, 0, stream);
}

// Round 5
// 92.106 us; speedup vs baseline: 2.6920x; 2.6920x over previous
//
#include <hip/hip_runtime.h>
#include <math.h>

#define V_ 32000
#define E_ 1024
#define H_ 1024
#define S_ 2048

typedef __attribute__((ext_vector_type(8))) short bf16x8;
typedef __attribute__((ext_vector_type(8))) unsigned short u16x8;
typedef __attribute__((ext_vector_type(4))) float f32x4;

typedef __attribute__((address_space(1))) const unsigned int gu32;
typedef __attribute__((address_space(3))) unsigned int lu32;

__device__ __forceinline__ float sigmoidf_(float x) { return 1.0f / (1.0f + expf(-x)); }

__device__ __forceinline__ unsigned short f2bf(float f) {
    unsigned int u = __builtin_bit_cast(unsigned int, f);
    unsigned int r = (u + 0x7fffu + ((u >> 16) & 1u)) >> 16;
    return (unsigned short)r;
}
__device__ __forceinline__ float bf2f(unsigned short u) {
    return __builtin_bit_cast(float, ((unsigned int)u) << 16);
}
__device__ __forceinline__ u16x8 pack8(float4 a, float4 b) {
    u16x8 p;
    p[0] = f2bf(a.x); p[1] = f2bf(a.y); p[2] = f2bf(a.z); p[3] = f2bf(a.w);
    p[4] = f2bf(b.x); p[5] = f2bf(b.y); p[6] = f2bf(b.z); p[7] = f2bf(b.w);
    return p;
}
__device__ __forceinline__ void gload16(const void* g, void* l) {
    __builtin_amdgcn_global_load_lds((gu32*)g, (lu32*)l, 16, 0, 0);
}

// ---------------- KA: k1 LSTM (blocks 0..1023) || bf16 conversion (1024..1535) ----------------
__global__ __launch_bounds__(256) void kA(
    const float* __restrict__ W_ih, const float* __restrict__ W_hh,
    const float* __restrict__ b_ih, const float* __restrict__ b_hh,
    const float* __restrict__ last_context, const float* __restrict__ emb,
    const int* __restrict__ word, const float* __restrict__ h0,
    const float* __restrict__ c0, const float* __restrict__ enc,
    const float* __restrict__ W_attn,
    float* __restrict__ out_ht, float* __restrict__ out_c,
    float* __restrict__ ws_ht, unsigned short* __restrict__ encb,
    unsigned short* __restrict__ wab, float* __restrict__ ws_ctx)
{
    int b = blockIdx.x, tid = threadIdx.x;
    int wave = tid >> 6, lane = tid & 63;
    if (b < 1024) {
        __shared__ float sbuf[4];
        int j = b;
        const float* embrow = emb + (size_t)word[0] * E_;
        int row = j + wave * H_;
        const float* wi = W_ih + (size_t)row * (E_ + H_);
        const float* wh = W_hh + (size_t)row * H_;
        float acc = 0.f;
        #pragma unroll
        for (int it = 0; it < 8; ++it) {
            int idx = (lane + it * 64) * 4;
            float4 wv = *(const float4*)(wi + idx);
            float4 xv = (idx < H_) ? *(const float4*)(last_context + idx)
                                   : *(const float4*)(embrow + (idx - H_));
            acc = fmaf(wv.x, xv.x, acc); acc = fmaf(wv.y, xv.y, acc);
            acc = fmaf(wv.z, xv.z, acc); acc = fmaf(wv.w, xv.w, acc);
        }
        #pragma unroll
        for (int it = 0; it < 4; ++it) {
            int idx = (lane + it * 64) * 4;
            float4 wv = *(const float4*)(wh + idx);
            float4 hv = *(const float4*)(h0 + idx);
            acc = fmaf(wv.x, hv.x, acc); acc = fmaf(wv.y, hv.y, acc);
            acc = fmaf(wv.z, hv.z, acc); acc = fmaf(wv.w, hv.w, acc);
        }
        #pragma unroll
        for (int m = 32; m; m >>= 1) acc += __shfl_down(acc, m, 64);
        if (lane == 0) sbuf[wave] = acc;
        __syncthreads();
        if (tid < 4 && b == 0) {
            // zero ctx accumulator (1024 floats over 4 active threads x 256? no: do below)
        }
        if (tid == 0) {
            float gi = sbuf[0] + b_ih[j]          + b_hh[j];
            float gf = sbuf[1] + b_ih[j + H_]     + b_hh[j + H_];
            float gg = sbuf[2] + b_ih[j + 2*H_]   + b_hh[j + 2*H_];
            float go = sbuf[3] + b_ih[j + 3*H_]   + b_hh[j + 3*H_];
            float c  = sigmoidf_(gf) * c0[j] + sigmoidf_(gi) * tanhf(gg);
            float ht = sigmoidf_(go) * tanhf(c);
            out_c[j]  = c;
            out_ht[j] = ht;
            ws_ht[j]  = ht;
        }
        if (b == 0) {
            ws_ctx[tid] = 0.f;
            ws_ctx[tid + 256] = 0.f;
            ws_ctx[tid + 512] = 0.f;
            ws_ctx[tid + 768] = 0.f;
        }
    } else {
        // conversion: 393216 16B-granules, blocks 1024..1535, 3 granules/thread
        int cid = (b - 1024) * 256 + tid;
        const int ENC_CH = (S_ * E_) / 8;   // 262144
        #pragma unroll
        for (int i = 0; i < 3; ++i) {
            int idx = cid + i * 131072;
            const float* src;
            unsigned short* dst;
            if (idx < ENC_CH) {
                src = enc + (size_t)idx * 8;
                dst = encb + (size_t)idx * 8;
            } else {
                int w = idx - ENC_CH;
                int h = w >> 7, off = (w & 127) * 8;
                src = W_attn + (size_t)h * (E_ + H_) + H_ + off;
                dst = wab + (size_t)h * E_ + off;
            }
            float4 a = *(const float4*)src;
            float4 bq = *(const float4*)(src + 4);
            *(u16x8*)dst = pack8(a, bq);
        }
    }
}

// ---------------- KB: q = Wa_h @ ht + b_attn ----------------
__global__ __launch_bounds__(64) void kB(
    const float* __restrict__ W_attn, const float* __restrict__ b_attn,
    const float* __restrict__ ht, float* __restrict__ q)
{
    int h = blockIdx.x;
    int lane = threadIdx.x;
    const float* row = W_attn + (size_t)h * (E_ + H_);
    float acc = 0.f;
    #pragma unroll
    for (int it = 0; it < 4; ++it) {
        int idx = (lane + it * 64) * 4;
        float4 wv = *(const float4*)(row + idx);
        float4 hv = *(const float4*)(ht + idx);
        acc = fmaf(wv.x, hv.x, acc); acc = fmaf(wv.y, hv.y, acc);
        acc = fmaf(wv.z, hv.z, acc); acc = fmaf(wv.w, hv.w, acc);
    }
    #pragma unroll
    for (int m = 32; m; m >>= 1) acc += __shfl_down(acc, m, 64);
    if (lane == 0) q[h] = acc + b_attn[h];
}

// ---------------- KC: scores partials = tanh(enc @ Wa_e^T + q) @ v ----------------
__global__ __launch_bounds__(256) void kC(
    const unsigned short* __restrict__ encb, const unsigned short* __restrict__ wab,
    const float* __restrict__ q, const float* __restrict__ v,
    float* __restrict__ spart)
{
    __shared__ unsigned short As[2][128 * 64];
    __shared__ unsigned short Bs[2][64 * 64];
    int s0 = blockIdx.x * 128, h0 = blockIdx.y * 64;
    int tid = threadIdx.x;
    int wave = tid >> 6, lane = tid & 63;
    int wr = (wave >> 1) * 64, wc = (wave & 1) * 32;

    int srow = tid >> 3;
    int lch  = ((tid & 7) ^ (srow & 7)) * 8;
    const unsigned short* aSrc[4];
    #pragma unroll
    for (int jj = 0; jj < 4; ++jj)
        aSrc[jj] = encb + (size_t)(s0 + jj * 32 + srow) * E_ + lch;
    const unsigned short* bSrc[2];
    #pragma unroll
    for (int jj = 0; jj < 2; ++jj)
        bSrc[jj] = wab + (size_t)(h0 + jj * 32 + srow) * E_ + lch;

    int fc = lane & 15, g = lane >> 4;
    int aRow[4], bRow[2], pc[2];
    #pragma unroll
    for (int m = 0; m < 4; ++m) aRow[m] = (wr + m * 16 + fc) * 64;
    #pragma unroll
    for (int n = 0; n < 2; ++n) bRow[n] = (wc + n * 16 + fc) * 64;
    #pragma unroll
    for (int kk = 0; kk < 2; ++kk) pc[kk] = ((kk * 4 + g) ^ (fc & 7)) * 8;

    f32x4 acc[4][2];
    #pragma unroll
    for (int m = 0; m < 4; ++m)
        #pragma unroll
        for (int n = 0; n < 2; ++n)
            acc[m][n] = (f32x4){0.f, 0.f, 0.f, 0.f};

    #pragma unroll
    for (int jj = 0; jj < 4; ++jj) gload16(aSrc[jj], &As[0][jj * 2048 + tid * 8]);
    #pragma unroll
    for (int jj = 0; jj < 2; ++jj) gload16(bSrc[jj], &Bs[0][jj * 2048 + tid * 8]);
    __syncthreads();

    int cur = 0;
    for (int t = 0; t < 16; ++t) {
        if (t < 15) {
            int k0 = (t + 1) * 64;
            #pragma unroll
            for (int jj = 0; jj < 4; ++jj)
                gload16(aSrc[jj] + k0, &As[cur ^ 1][jj * 2048 + tid * 8]);
            #pragma unroll
            for (int jj = 0; jj < 2; ++jj)
                gload16(bSrc[jj] + k0, &Bs[cur ^ 1][jj * 2048 + tid * 8]);
        }
        #pragma unroll
        for (int kk = 0; kk < 2; ++kk) {
            bf16x8 af[4], bf2[2];
            #pragma unroll
            for (int m = 0; m < 4; ++m) af[m] = *(const bf16x8*)&As[cur][aRow[m] + pc[kk]];
            #pragma unroll
            for (int n = 0; n < 2; ++n) bf2[n] = *(const bf16x8*)&Bs[cur][bRow[n] + pc[kk]];
            #pragma unroll
            for (int m = 0; m < 4; ++m)
                #pragma unroll
                for (int n = 0; n < 2; ++n)
                    acc[m][n] = __builtin_amdgcn_mfma_f32_16x16x32_bf16(
                        af[m], bf2[n], acc[m][n], 0, 0, 0);
        }
        __syncthreads();
        cur ^= 1;
    }

    float qv[2], vv[2];
    #pragma unroll
    for (int n = 0; n < 2; ++n) {
        int col = h0 + wc + n * 16 + fc;
        qv[n] = q[col];
        vv[n] = v[col];
    }
    int part = blockIdx.y * 2 + (wave & 1);
    #pragma unroll
    for (int m = 0; m < 4; ++m) {
        #pragma unroll
        for (int j = 0; j < 4; ++j) {
            float p = 0.f;
            #pragma unroll
            for (int n = 0; n < 2; ++n)
                p += tanhf(acc[m][n][j] + qv[n]) * vv[n];
            #pragma unroll
            for (int mask = 8; mask; mask >>= 1) p += __shfl_xor(p, mask, 64);
            if (fc == 0)
                spart[(size_t)(s0 + wr + m * 16 + g * 4 + j) * 32 + part] = p;
        }
    }
}

// ---------------- KD: e = exp(sum spart); gS partials; ctxU += e * enc ----------------
// 128 blocks x 256 threads; block handles 16 s-rows.
__global__ __launch_bounds__(256) void kD(
    const float* __restrict__ spart, const unsigned short* __restrict__ encb,
    float* __restrict__ expw, float* __restrict__ gpart, float* __restrict__ ctx)
{
    __shared__ float esh[16];
    int b = blockIdx.x, tid = threadIdx.x;
    int s0 = b * 16;
    int sl = tid >> 4, pp = tid & 15;
    float vsum = spart[(size_t)(s0 + sl) * 32 + pp]
               + spart[(size_t)(s0 + sl) * 32 + pp + 16];
    #pragma unroll
    for (int mask = 8; mask; mask >>= 1) vsum += __shfl_xor(vsum, mask, 64);
    if (pp == 0) {
        float e = expf(vsum);
        expw[s0 + sl] = e;
        esh[sl] = e;
    }
    __syncthreads();
    if (tid == 0) {
        float bs = 0.f;
        #pragma unroll
        for (int i = 0; i < 16; ++i) bs += esh[i];
        gpart[b] = bs;
    }
    // ctxU accumulation: thread handles 4 e-columns
    int e0 = tid * 4;
    float a0 = 0.f, a1 = 0.f, a2 = 0.f, a3 = 0.f;
    #pragma unroll
    for (int ss = 0; ss < 16; ++ss) {
        const unsigned short* r = encb + (size_t)(s0 + ss) * E_ + e0;
        ushort4 u = *(const ushort4*)r;
        float w = esh[ss];
        a0 = fmaf(w, bf2f(u.x), a0);
        a1 = fmaf(w, bf2f(u.y), a1);
        a2 = fmaf(w, bf2f(u.z), a2);
        a3 = fmaf(w, bf2f(u.w), a3);
    }
    atomicAdd(&ctx[e0 + 0], a0);
    atomicAdd(&ctx[e0 + 1], a1);
    atomicAdd(&ctx[e0 + 2], a2);
    atomicAdd(&ctx[e0 + 3], a3);
}

// ---------------- KE: ht_tilda = tanh(W_ah @ [ctxU/gS, ht] + b_ah); out_w ----------------
// blocks 0..1023: one W_ah row each. blocks 1024..1031: out_w.
__global__ __launch_bounds__(64) void kE(
    const float* __restrict__ W_ah, const float* __restrict__ b_ah,
    const float* __restrict__ ctx, const float* __restrict__ ht,
    const float* __restrict__ gpart, const float* __restrict__ expw,
    float* __restrict__ out_htt, float* __restrict__ ws_htt,
    float* __restrict__ out_w)
{
    int b = blockIdx.x;
    int lane = threadIdx.x;
    // invS from 128 partials (deterministic, same in every block)
    float gsum = gpart[lane] + gpart[lane + 64];
    #pragma unroll
    for (int m = 32; m; m >>= 1) gsum += __shfl_xor(gsum, m, 64);
    float invS = 1.0f / gsum;
    if (b >= 1024) {
        int s = (b - 1024) * 256 + lane * 4;
        float4 e4 = *(const float4*)(expw + s);
        float4 w4 = { e4.x * invS, e4.y * invS, e4.z * invS, e4.w * invS };
        *(float4*)(out_w + s) = w4;
        return;
    }
    const float* row = W_ah + (size_t)b * (E_ + H_);
    float acc = 0.f;
    #pragma unroll
    for (int it = 0; it < 8; ++it) {
        int idx = (lane + it * 64) * 4;
        float4 wv = *(const float4*)(row + idx);
        float4 xv;
        if (idx < E_) {
            float4 cv = *(const float4*)(ctx + idx);
            xv = (float4){ cv.x * invS, cv.y * invS, cv.z * invS, cv.w * invS };
        } else {
            xv = *(const float4*)(ht + idx - E_);
        }
        acc = fmaf(wv.x, xv.x, acc); acc = fmaf(wv.y, xv.y, acc);
        acc = fmaf(wv.z, xv.z, acc); acc = fmaf(wv.w, xv.w, acc);
    }
    #pragma unroll
    for (int m = 32; m; m >>= 1) acc += __shfl_down(acc, m, 64);
    if (lane == 0) {
        float val = tanhf(acc + b_ah[b]);
        out_htt[b] = val;
        ws_htt[b]  = val;
    }
}

// ---------------- KF: logits = W_out @ ht_tilda + b_out; per-block expsum ----------------
__global__ __launch_bounds__(256) void kF(
    const float* __restrict__ W_out, const float* __restrict__ b_out,
    const float* __restrict__ ht_tilda, float* __restrict__ logits,
    float* __restrict__ lpart)
{
    __shared__ float wes[4];
    int b = blockIdx.x;
    int wave = threadIdx.x >> 6, lane = threadIdx.x & 63;
    int row = b * 4 + wave;
    const float* wr = W_out + (size_t)row * H_;
    float acc = 0.f;
    #pragma unroll
    for (int it = 0; it < 4; ++it) {
        int idx = (lane + it * 64) * 4;
        float4 wv = *(const float4*)(wr + idx);
        float4 hv = *(const float4*)(ht_tilda + idx);
        acc = fmaf(wv.x, hv.x, acc); acc = fmaf(wv.y, hv.y, acc);
        acc = fmaf(wv.z, hv.z, acc); acc = fmaf(wv.w, hv.w, acc);
    }
    #pragma unroll
    for (int m = 32; m; m >>= 1) acc += __shfl_down(acc, m, 64);
    if (lane == 0) {
        float lg = acc + b_out[row];
        logits[row] = lg;
        wes[wave] = expf(lg);
    }
    __syncthreads();
    if (threadIdx.x == 0)
        lpart[b] = wes[0] + wes[1] + wes[2] + wes[3];
}

// ---------------- KG: lse = log(sum lpart); out -= lse ----------------
__global__ __launch_bounds__(256) void kG(
    float* __restrict__ out, const float* __restrict__ lpart)
{
    __shared__ float sred[4];
    int tid = threadIdx.x;
    float s = 0.f;
    for (int i = tid; i < 8000; i += 256) s += lpart[i];
    #pragma unroll
    for (int m = 32; m; m >>= 1) s += __shfl_down(s, m, 64);
    if ((tid & 63) == 0) sred[tid >> 6] = s;
    __syncthreads();
    float lse = logf(sred[0] + sred[1] + sred[2] + sred[3]);
    out[blockIdx.x * 256 + tid] -= lse;
}

extern "C" void kernel_launch(void* const* d_in, const int* in_sizes, int n_in,
                              void* d_out, int out_size, void* d_ws, size_t ws_size,
                              hipStream_t stream) {
    const float* enc          = (const float*)d_in[0];
    const int*   word         = (const int*)  d_in[1];
    const float* last_context = (const float*)d_in[2];
    const float* h0           = (const float*)d_in[3];
    const float* c0           = (const float*)d_in[4];
    const float* emb          = (const float*)d_in[5];
    const float* W_ih         = (const float*)d_in[6];
    const float* W_hh         = (const float*)d_in[7];
    const float* b_ih         = (const float*)d_in[8];
    const float* b_hh         = (const float*)d_in[9];
    const float* W_attn       = (const float*)d_in[10];
    const float* b_attn       = (const float*)d_in[11];
    const float* v            = (const float*)d_in[12];
    const float* W_ah         = (const float*)d_in[13];
    const float* b_ah         = (const float*)d_in[14];
    const float* W_out        = (const float*)d_in[15];
    const float* b_out        = (const float*)d_in[16];

    float* out        = (float*)d_out;
    float* out_logits = out;                 // 32000
    float* out_ht     = out + V_;            // 1024
    float* out_c      = out + V_ + H_;       // 1024
    float* out_htt    = out + V_ + 2 * H_;   // 1024
    float* out_w      = out + V_ + 3 * H_;   // 2048

    float* ws      = (float*)d_ws;
    float* ws_ht   = ws;             // 1024
    float* ws_q    = ws + 1024;      // 1024
    float* ws_expw = ws + 2048;      // 2048
    float* ws_ctx  = ws + 4096;      // 1024
    float* ws_htt  = ws + 5120;      // 1024
    float* ws_gp   = ws + 6144;      // 128
    float* ws_lp   = ws + 8192;      // 8000
    float* ws_sp   = ws + 16384;     // 2048*32
    unsigned short* encb = (unsigned short*)(ws + 81920);  // 2048*1024 bf16
    unsigned short* wab  = encb + (size_t)S_ * E_;         // 1024*1024 bf16

    kA<<<1536, 256, 0, stream>>>(W_ih, W_hh, b_ih, b_hh, last_context, emb, word,
                                 h0, c0, enc, W_attn, out_ht, out_c, ws_ht,
                                 encb, wab, ws_ctx);
    kB<<<1024, 64, 0, stream>>>(W_attn, b_attn, ws_ht, ws_q);
    kC<<<dim3(S_ / 128, H_ / 64), 256, 0, stream>>>(encb, wab, ws_q, v, ws_sp);
    kD<<<128, 256, 0, stream>>>(ws_sp, encb, ws_expw, ws_gp, ws_ctx);
    kE<<<1032, 64, 0, stream>>>(W_ah, b_ah, ws_ctx, ws_ht, ws_gp, ws_expw,
                                out_htt, ws_htt, out_w);
    kF<<<8000, 256, 0, stream>>>(W_out, b_out, ws_htt, out_logits, ws_lp);
    kG<<<125, 256, 0, stream>>>(out_logits, ws_lp);
}